// Round 1
// baseline (22123.244 us; speedup 1.0000x reference)
//
#include <hip/hip_runtime.h>

namespace {

constexpr int H_ = 64;    // hidden
constexpr int R_ = 32;    // rank
constexpr int B_ = 64;
constexpr int C_ = 256;
constexpr int T_ = 512;
constexpr int N_ = B_ * C_;   // 16384 sequences

constexpr int GRU_THREADS = 512;  // 8 waves
constexpr int IPW = 8;            // hidden outputs per wave (64 / 8 waves)
constexpr int TC = 16;            // x time-tile

__device__ __forceinline__ float sigmoidf_(float a) {
    return 1.0f / (1.0f + __expf(-a));
}
__device__ __forceinline__ float tanhf_(float a) {
    float e = __expf(2.0f * a);
    return 1.0f - 2.0f / (e + 1.0f);
}

// ---------------------------------------------------------------------------
// GRU scan: 256 blocks x 512 threads. Block = 64 sequences.
// lane (tid&63) = sequence, wave (tid>>6) = 8-output slice.
// h stored transposed hT[j][s] (+1 pad) so dot-loop reads are conflict-free.
// Weights read via wave-uniform (readfirstlane) indices -> s_load broadcast.
// ---------------------------------------------------------------------------
__global__ __launch_bounds__(GRU_THREADS)
void gru_scan_kernel(const float* __restrict__ x,
                     const float* __restrict__ Wih0,
                     const float* __restrict__ Whh0,
                     const float* __restrict__ bih0,
                     const float* __restrict__ bhh0,
                     const float* __restrict__ Wih1,
                     const float* __restrict__ Whh1,
                     const float* __restrict__ bih1,
                     const float* __restrict__ bhh1,
                     float* __restrict__ hT_out)
{
    __shared__ float h0T[2][H_][H_ + 1];
    __shared__ float h1T[2][H_][H_ + 1];
    __shared__ float xT[TC][H_ + 1];

    const int tid = threadIdx.x;
    const int s   = tid & 63;
    const int wv  = tid >> 6;
    const int n0  = blockIdx.x * 64;

    // zero-init both ping-pong buffers
    for (int p = tid; p < 2 * H_ * (H_ + 1); p += GRU_THREADS) {
        (&h0T[0][0][0])[p] = 0.0f;
        (&h1T[0][0][0])[p] = 0.0f;
    }

    // wave-uniform output-slice base
    const int i0 = __builtin_amdgcn_readfirstlane(wv * IPW);
    const float* W0r = Whh0 + (0   + i0) * H_;
    const float* W0z = Whh0 + (64  + i0) * H_;
    const float* W0n = Whh0 + (128 + i0) * H_;
    const float* X1r = Wih1 + (0   + i0) * H_;
    const float* X1z = Wih1 + (64  + i0) * H_;
    const float* X1n = Wih1 + (128 + i0) * H_;
    const float* H1r = Whh1 + (0   + i0) * H_;
    const float* H1z = Whh1 + (64  + i0) * H_;
    const float* H1n = Whh1 + (128 + i0) * H_;

    __syncthreads();

    int cur = 0;
    for (int t0 = 0; t0 < T_; t0 += TC) {
        // stage x tile (coalesced on t)
        for (int p = tid; p < TC * 64; p += GRU_THREADS) {
            int tt = p & (TC - 1);
            int ss = p >> 4;
            xT[tt][ss] = x[(size_t)(n0 + ss) * T_ + (t0 + tt)];
        }
        __syncthreads();

        for (int dt = 0; dt < TC; ++dt) {
            const int nxt = cur ^ 1;
            // ---------------- layer 0 ----------------
            float ar[IPW], az[IPW], an[IPW];
            #pragma unroll
            for (int ii = 0; ii < IPW; ++ii) {
                ar[ii] = bhh0[i0 + ii];
                az[ii] = bhh0[64 + i0 + ii];
                an[ii] = bhh0[128 + i0 + ii];
            }
            #pragma unroll 4
            for (int j = 0; j < H_; ++j) {
                float hj = h0T[cur][j][s];
                #pragma unroll
                for (int ii = 0; ii < IPW; ++ii) {
                    ar[ii] = __fmaf_rn(W0r[ii * H_ + j], hj, ar[ii]);
                    az[ii] = __fmaf_rn(W0z[ii * H_ + j], hj, az[ii]);
                    an[ii] = __fmaf_rn(W0n[ii * H_ + j], hj, an[ii]);
                }
            }
            float xs = xT[dt][s];
            #pragma unroll
            for (int ii = 0; ii < IPW; ++ii) {
                int i = i0 + ii;
                float gxr = __fmaf_rn(Wih0[i],       xs, bih0[i]);
                float gxz = __fmaf_rn(Wih0[64 + i],  xs, bih0[64 + i]);
                float gxn = __fmaf_rn(Wih0[128 + i], xs, bih0[128 + i]);
                float r = sigmoidf_(gxr + ar[ii]);
                float z = sigmoidf_(gxz + az[ii]);
                float n = tanhf_(gxn + r * an[ii]);
                float hold = h0T[cur][i][s];
                h0T[nxt][i][s] = (1.0f - z) * n + z * hold;
            }
            __syncthreads();   // h0_new visible

            // ---------------- layer 1 ----------------
            float xr[IPW], xz[IPW], xn[IPW], hr[IPW], hz[IPW], hn[IPW];
            #pragma unroll
            for (int ii = 0; ii < IPW; ++ii) {
                xr[ii] = bih1[i0 + ii];
                xz[ii] = bih1[64 + i0 + ii];
                xn[ii] = bih1[128 + i0 + ii];
                hr[ii] = bhh1[i0 + ii];
                hz[ii] = bhh1[64 + i0 + ii];
                hn[ii] = bhh1[128 + i0 + ii];
            }
            #pragma unroll 2
            for (int j = 0; j < H_; ++j) {
                float aj = h0T[nxt][j][s];
                float bj = h1T[cur][j][s];
                #pragma unroll
                for (int ii = 0; ii < IPW; ++ii) {
                    xr[ii] = __fmaf_rn(X1r[ii * H_ + j], aj, xr[ii]);
                    xz[ii] = __fmaf_rn(X1z[ii * H_ + j], aj, xz[ii]);
                    xn[ii] = __fmaf_rn(X1n[ii * H_ + j], aj, xn[ii]);
                    hr[ii] = __fmaf_rn(H1r[ii * H_ + j], bj, hr[ii]);
                    hz[ii] = __fmaf_rn(H1z[ii * H_ + j], bj, hz[ii]);
                    hn[ii] = __fmaf_rn(H1n[ii * H_ + j], bj, hn[ii]);
                }
            }
            #pragma unroll
            for (int ii = 0; ii < IPW; ++ii) {
                int i = i0 + ii;
                float r = sigmoidf_(xr[ii] + hr[ii]);
                float z = sigmoidf_(xz[ii] + hz[ii]);
                float n = tanhf_(xn[ii] + r * hn[ii]);
                float hold = h1T[cur][i][s];
                h1T[nxt][i][s] = (1.0f - z) * n + z * hold;
            }
            __syncthreads();
            cur = nxt;
        }
    }

    // write final top-layer hidden state, coalesced
    for (int p = tid; p < 64 * H_; p += GRU_THREADS) {
        int i  = p & 63;
        int ss = p >> 6;
        hT_out[(size_t)(n0 + ss) * H_ + i] = h1T[cur][i][ss];
    }
}

// ---------------------------------------------------------------------------
// Heads: mu, softplus(d), v (R=32), resid = y - mu. One thread per sequence.
// ---------------------------------------------------------------------------
__global__ __launch_bounds__(256)
void heads_kernel(const float* __restrict__ hT,
                  const float* __restrict__ y,
                  const float* __restrict__ Wm, const float* __restrict__ bm,
                  const float* __restrict__ Wd, const float* __restrict__ bd,
                  const float* __restrict__ Wv, const float* __restrict__ bv,
                  float* __restrict__ v_out,
                  float* __restrict__ dd_out,
                  float* __restrict__ r_out)
{
    const int n = blockIdx.x * 256 + threadIdx.x;
    const float* h = hT + (size_t)n * H_;

    float hreg[H_];
    #pragma unroll
    for (int j = 0; j < H_; j += 4) {
        float4 q = *(const float4*)(h + j);
        hreg[j] = q.x; hreg[j + 1] = q.y; hreg[j + 2] = q.z; hreg[j + 3] = q.w;
    }
    float mu = bm[0], dv = bd[0];
    #pragma unroll
    for (int j = 0; j < H_; ++j) {
        mu = __fmaf_rn(Wm[j], hreg[j], mu);
        dv = __fmaf_rn(Wd[j], hreg[j], dv);
    }
    r_out[n]  = y[n] - mu;
    dd_out[n] = log1pf(__expf(dv));   // softplus

    for (int k = 0; k < R_; ++k) {
        float acc = bv[k];
        #pragma unroll
        for (int j = 0; j < H_; ++j)
            acc = __fmaf_rn(Wv[k * H_ + j], hreg[j], acc);
        v_out[(size_t)n * R_ + k] = acc;
    }
}

__device__ __forceinline__ float block_reduce_sum256(float* red, int tid, float val)
{
    red[tid] = val;
    __syncthreads();
    for (int off = 128; off > 0; off >>= 1) {
        if (tid < off) red[tid] += red[tid + off];
        __syncthreads();
    }
    float r = red[0];
    __syncthreads();
    return r;
}

// ---------------------------------------------------------------------------
// Per-batch Woodbury: sigma = V V^T + D (V: 256x32, D diag).
// quad  = r^T D^-1 r - u^T M^-1 u,  u = V^T D^-1 r,  M = I + V^T D^-1 V
// logdet= sum log d + logdet M  (M via 32x32 Cholesky)
// ---------------------------------------------------------------------------
__global__ __launch_bounds__(256)
void woodbury_kernel(const float* __restrict__ v_in,
                     const float* __restrict__ dd_in,
                     const float* __restrict__ r_in,
                     float* __restrict__ batch_out)
{
    __shared__ float Vl[C_][R_ + 1];
    __shared__ float Vw[C_][R_ + 1];
    __shared__ float wi[C_];
    __shared__ float rl[C_];
    __shared__ float red[256];
    __shared__ float MA[R_][R_ + 1];
    __shared__ float uA[R_], yA[R_], wA[R_];

    const int tid = threadIdx.x;
    const int nb  = blockIdx.x * C_;

    for (int p = tid; p < C_ * R_; p += 256) {
        int c = p >> 5, k = p & 31;
        Vl[c][k] = v_in[(size_t)(nb + c) * R_ + k];
    }
    float dval = dd_in[nb + tid];
    float winv = 1.0f / dval;
    float rv   = r_in[nb + tid];
    wi[tid] = winv;
    rl[tid] = rv;
    __syncthreads();

    for (int p = tid; p < C_ * R_; p += 256) {
        int c = p >> 5, k = p & 31;
        Vw[c][k] = Vl[c][k] * wi[c];
    }
    __syncthreads();

    float slogd = block_reduce_sum256(red, tid, __logf(dval));
    float rDr   = block_reduce_sum256(red, tid, rv * rv * winv);

    // M = I + V^T D^-1 V  (1024 entries, 4 per thread)
    #pragma unroll
    for (int e = 0; e < 4; ++e) {
        int p = tid + e * 256;
        int i = p >> 5, j = p & 31;
        float acc = (i == j) ? 1.0f : 0.0f;
        for (int c = 0; c < C_; ++c)
            acc = __fmaf_rn(Vw[c][i], Vl[c][j], acc);
        MA[i][j] = acc;
    }
    // u = V^T D^-1 r
    if (tid < R_) {
        float acc = 0.0f;
        for (int c = 0; c < C_; ++c)
            acc = __fmaf_rn(Vw[c][tid], rl[c], acc);
        uA[tid] = acc;
    }
    __syncthreads();

    // Cholesky (lower) of MA
    for (int k = 0; k < R_; ++k) {
        if (tid == 0) MA[k][k] = sqrtf(MA[k][k]);
        __syncthreads();
        if (tid > k && tid < R_) MA[tid][k] /= MA[k][k];
        __syncthreads();
        if (tid > k && tid < R_) {
            float ljk = MA[tid][k];
            for (int i2 = k + 1; i2 <= tid; ++i2)
                MA[tid][i2] -= ljk * MA[i2][k];
        }
        __syncthreads();
    }
    float ldm = block_reduce_sum256(red, tid,
                    (tid < R_) ? 2.0f * __logf(MA[tid][tid]) : 0.0f);

    if (tid == 0) {
        // solve L L^T w = u
        for (int k = 0; k < R_; ++k) {
            float sv = uA[k];
            for (int i2 = 0; i2 < k; ++i2) sv -= MA[k][i2] * yA[i2];
            yA[k] = sv / MA[k][k];
        }
        for (int k = R_ - 1; k >= 0; --k) {
            float sv = yA[k];
            for (int i2 = k + 1; i2 < R_; ++i2) sv -= MA[i2][k] * wA[i2];
            wA[k] = sv / MA[k][k];
        }
        float uw = 0.0f;
        for (int k = 0; k < R_; ++k) uw += wA[k] * uA[k];
        batch_out[blockIdx.x] = (rDr - uw) + slogd + ldm;
    }
}

__global__ void finalize_kernel(const float* __restrict__ bws, float* __restrict__ out)
{
    float v = bws[threadIdx.x];
    #pragma unroll
    for (int off = 32; off > 0; off >>= 1)
        v += __shfl_down(v, off, 64);
    if (threadIdx.x == 0) out[0] = v * (1.0f / 64.0f);
}

} // anonymous namespace

extern "C" void kernel_launch(void* const* d_in, const int* in_sizes, int n_in,
                              void* d_out, int out_size, void* d_ws, size_t ws_size,
                              hipStream_t stream)
{
    const float* x    = (const float*)d_in[0];
    const float* y    = (const float*)d_in[1];
    const float* Wih0 = (const float*)d_in[2];
    const float* Whh0 = (const float*)d_in[3];
    const float* bih0 = (const float*)d_in[4];
    const float* bhh0 = (const float*)d_in[5];
    const float* Wih1 = (const float*)d_in[6];
    const float* Whh1 = (const float*)d_in[7];
    const float* bih1 = (const float*)d_in[8];
    const float* bhh1 = (const float*)d_in[9];
    const float* Wm   = (const float*)d_in[10];
    const float* bm   = (const float*)d_in[11];
    const float* Wd   = (const float*)d_in[12];
    const float* bd   = (const float*)d_in[13];
    const float* Wv   = (const float*)d_in[14];
    const float* bv   = (const float*)d_in[15];

    char* ws = (char*)d_ws;
    float* hT    = (float*)ws;                                    // N*64
    float* v_ws  = (float*)(ws + (size_t)N_ * H_ * 4);            // N*32
    float* dd_ws = (float*)(ws + (size_t)N_ * (H_ + R_) * 4);     // N
    float* r_ws  = dd_ws + N_;                                    // N
    float* b_ws  = r_ws + N_;                                     // B_

    gru_scan_kernel<<<N_ / 64, GRU_THREADS, 0, stream>>>(
        x, Wih0, Whh0, bih0, bhh0, Wih1, Whh1, bih1, bhh1, hT);
    heads_kernel<<<N_ / 256, 256, 0, stream>>>(
        hT, y, Wm, bm, Wd, bd, Wv, bv, v_ws, dd_ws, r_ws);
    woodbury_kernel<<<B_, 256, 0, stream>>>(v_ws, dd_ws, r_ws, b_ws);
    finalize_kernel<<<1, 64, 0, stream>>>(b_ws, (float*)d_out);
}

// Round 2
// 1849.860 us; speedup vs baseline: 11.9594x; 11.9594x over previous
//
#include <hip/hip_runtime.h>

typedef __attribute__((ext_vector_type(8))) _Float16 f16x8;
typedef __attribute__((ext_vector_type(4))) float f32x4;

namespace {

constexpr int H_ = 64;
constexpr int R_ = 32;
constexpr int B_ = 64;
constexpr int C_ = 256;
constexpr int T_ = 512;
constexpr int N_ = B_ * C_;   // 16384 sequences

#define MFMA16(a, b, c) __builtin_amdgcn_mfma_f32_16x16x32_f16((a), (b), (c), 0, 0, 0)

__device__ __forceinline__ float sigf(float v) {
    return 1.0f / (1.0f + __expf(-v));
}
// tanh(a) = 2*sigmoid(2a) - 1  (graceful at +/-inf)
__device__ __forceinline__ float tanhf_(float a) {
    return __fmaf_rn(2.0f, sigf(2.0f * a), -1.0f);
}

// ---------------------------------------------------------------------------
// Pack GRU weights into B-fragment-linear fp16.
// Frag pairs (kk = f&1 selects K-chunk of 32):
//  f0-1 : Whh0 r     f2-3 : Whh0 z     f4-5 : Whh0 n
//  f6-7 : Wih1 r     f8-9 : Whh1 r
//  f10-11: Wih1 z    f12-13: Whh1 z
//  f14-15: Wih1 n    f16-17: Whh1 n
// Layout: packed[((w*18 + f)*512) + lane*8 + j], k = kk*32 + (lane>>4)*8 + j,
// col(out row) = hb + (lane&15) (+gate offset).
// ---------------------------------------------------------------------------
__global__ void pack_weights_kernel(const float* __restrict__ Whh0,
                                    const float* __restrict__ Wih1,
                                    const float* __restrict__ Whh1,
                                    _Float16* __restrict__ packed)
{
    const int b = blockIdx.x;          // 0..71
    const int w = b / 18, f = b % 18;
    const int l = threadIdx.x;         // 0..63
    const int c = l & 15, g = l >> 4;
    const int hb = w * 16;
    const int kk = f & 1;
    const float* src = Whh0;
    int row = 0;
    switch (f >> 1) {
        case 0: src = Whh0; row = hb + c;        break;
        case 1: src = Whh0; row = 64 + hb + c;   break;
        case 2: src = Whh0; row = 128 + hb + c;  break;
        case 3: src = Wih1; row = hb + c;        break;
        case 4: src = Whh1; row = hb + c;        break;
        case 5: src = Wih1; row = 64 + hb + c;   break;
        case 6: src = Whh1; row = 64 + hb + c;   break;
        case 7: src = Wih1; row = 128 + hb + c;  break;
        case 8: src = Whh1; row = 128 + hb + c;  break;
    }
    _Float16* dst = packed + ((size_t)(w * 18 + f) * 512) + (size_t)l * 8;
    #pragma unroll
    for (int j = 0; j < 8; ++j) {
        int k = kk * 32 + g * 8 + j;
        dst[j] = (_Float16)src[row * 64 + k];
    }
}

// ---------------------------------------------------------------------------
// MFMA GRU scan. Block = 16 sequences, 4 waves. Wave w owns hid-slice w*16..+15.
// Weights resident in registers (18 B-frags/lane). h-state fp32 in C-layout
// registers; fp16 staging in LDS for the A-operand round trip.
// ---------------------------------------------------------------------------
__global__ __launch_bounds__(256)
void gru_mfma_kernel(const float* __restrict__ x,
                     const _Float16* __restrict__ packedW,
                     const float* __restrict__ Wih0,
                     const float* __restrict__ bih0,
                     const float* __restrict__ bhh0,
                     const float* __restrict__ bih1,
                     const float* __restrict__ bhh1,
                     float* __restrict__ hT_out)
{
    __shared__ __align__(16) _Float16 h0s[2][16][72];   // padded: row stride 144 B
    __shared__ __align__(16) _Float16 h1s[2][16][72];
    __shared__ float xs_[32][17];

    const int tid = threadIdx.x;
    const int l = tid & 63;
    const int w = tid >> 6;
    const int c = l & 15, g = l >> 4;
    const int hb = w * 16;
    const int hid = hb + c;
    const int n0 = blockIdx.x * 16;

    // resident B fragments
    f16x8 B[18];
    {
        const f16x8* bp = (const f16x8*)(packedW + (size_t)w * 18 * 512);
        #pragma unroll
        for (int f = 0; f < 18; ++f) B[f] = bp[f * 64 + l];
    }

    // per-lane constants
    const float wr0 = Wih0[hid], wz0 = Wih0[64 + hid], wn0 = Wih0[128 + hid];
    const float b0r  = bhh0[hid] + bih0[hid];
    const float b0z  = bhh0[64 + hid] + bih0[64 + hid];
    const float b0nh = bhh0[128 + hid];
    const float b0nx = bih0[128 + hid];
    const float b1r  = bih1[hid] + bhh1[hid];
    const float b1z  = bih1[64 + hid] + bhh1[64 + hid];
    const float b1nx = bih1[128 + hid];
    const float b1nh = bhh1[128 + hid];

    for (int p = tid; p < 2 * 16 * 72; p += 256) {
        (&h0s[0][0][0])[p] = (_Float16)0.0f;
        (&h1s[0][0][0])[p] = (_Float16)0.0f;
    }
    float h0st[4] = {0.f, 0.f, 0.f, 0.f};
    float h1st[4] = {0.f, 0.f, 0.f, 0.f};
    __syncthreads();

    int cur = 0;
    for (int t0 = 0; t0 < T_; t0 += 32) {
        // stage x tile (coalesced on t)
        {
            int ss = tid >> 4;
            int tb = tid & 15;
            xs_[tb][ss]      = x[(size_t)(n0 + ss) * T_ + t0 + tb];
            xs_[tb + 16][ss] = x[(size_t)(n0 + ss) * T_ + t0 + tb + 16];
        }
        __syncthreads();

        for (int dt = 0; dt < 32; ++dt) {
            const int nxt = cur ^ 1;

            // ---- layer 0: gates = h0_prev @ Whh0^T (+bias in acc init) ----
            const _Float16* a0b = &h0s[cur][0][0];
            f16x8 a0k0 = *(const f16x8*)(a0b + c * 72 + g * 8);
            f16x8 a0k1 = *(const f16x8*)(a0b + c * 72 + 32 + g * 8);

            f32x4 accr = {b0r, b0r, b0r, b0r};
            f32x4 accz = {b0z, b0z, b0z, b0z};
            f32x4 accn = {b0nh, b0nh, b0nh, b0nh};
            accr = MFMA16(a0k0, B[0], accr);
            accz = MFMA16(a0k0, B[2], accz);
            accn = MFMA16(a0k0, B[4], accn);
            accr = MFMA16(a0k1, B[1], accr);
            accz = MFMA16(a0k1, B[3], accz);
            accn = MFMA16(a0k1, B[5], accn);

            #pragma unroll
            for (int q = 0; q < 4; ++q) {
                int seq = g * 4 + q;
                float xv = xs_[dt][seq];
                float r = sigf(__fmaf_rn(xv, wr0, accr[q]));
                float z = sigf(__fmaf_rn(xv, wz0, accz[q]));
                float nn = tanhf_(__fmaf_rn(xv, wn0, b0nx) + r * accn[q]);
                float hn = nn + z * (h0st[q] - nn);
                h0st[q] = hn;
                h0s[nxt][seq][hid] = (_Float16)hn;
            }
            __syncthreads();   // h0_new visible to all waves

            // ---- layer 1: gates = h0_new @ Wih1^T + h1_old @ Whh1^T ----
            const _Float16* a1b = &h0s[nxt][0][0];
            const _Float16* a2b = &h1s[cur][0][0];
            f16x8 an0 = *(const f16x8*)(a1b + c * 72 + g * 8);
            f16x8 an1 = *(const f16x8*)(a1b + c * 72 + 32 + g * 8);
            f16x8 ah0 = *(const f16x8*)(a2b + c * 72 + g * 8);
            f16x8 ah1 = *(const f16x8*)(a2b + c * 72 + 32 + g * 8);

            f32x4 r1  = {b1r, b1r, b1r, b1r};
            f32x4 z1  = {b1z, b1z, b1z, b1z};
            f32x4 xn1 = {b1nx, b1nx, b1nx, b1nx};
            f32x4 hn1 = {b1nh, b1nh, b1nh, b1nh};
            r1  = MFMA16(an0, B[6],  r1);
            z1  = MFMA16(an0, B[10], z1);
            xn1 = MFMA16(an0, B[14], xn1);
            r1  = MFMA16(an1, B[7],  r1);
            z1  = MFMA16(an1, B[11], z1);
            xn1 = MFMA16(an1, B[15], xn1);
            r1  = MFMA16(ah0, B[8],  r1);
            z1  = MFMA16(ah0, B[12], z1);
            hn1 = MFMA16(ah0, B[16], hn1);
            r1  = MFMA16(ah1, B[9],  r1);
            z1  = MFMA16(ah1, B[13], z1);
            hn1 = MFMA16(ah1, B[17], hn1);

            #pragma unroll
            for (int q = 0; q < 4; ++q) {
                int seq = g * 4 + q;
                float r = sigf(r1[q]);
                float z = sigf(z1[q]);
                float nn = tanhf_(xn1[q] + r * hn1[q]);
                float hn = nn + z * (h1st[q] - nn);
                h1st[q] = hn;
                h1s[nxt][seq][hid] = (_Float16)hn;
            }
            __syncthreads();
            cur = nxt;
        }
    }

    #pragma unroll
    for (int q = 0; q < 4; ++q) {
        int seq = g * 4 + q;
        hT_out[(size_t)(n0 + seq) * H_ + hid] = h1st[q];
    }
}

// ---------------------------------------------------------------------------
// Heads: mu, softplus(d), v (R=32), resid = y - mu. One thread per sequence.
// ---------------------------------------------------------------------------
__global__ __launch_bounds__(256)
void heads_kernel(const float* __restrict__ hT,
                  const float* __restrict__ y,
                  const float* __restrict__ Wm, const float* __restrict__ bm,
                  const float* __restrict__ Wd, const float* __restrict__ bd,
                  const float* __restrict__ Wv, const float* __restrict__ bv,
                  float* __restrict__ v_out,
                  float* __restrict__ dd_out,
                  float* __restrict__ r_out)
{
    const int n = blockIdx.x * 256 + threadIdx.x;
    const float* h = hT + (size_t)n * H_;

    float hreg[H_];
    #pragma unroll
    for (int j = 0; j < H_; j += 4) {
        float4 q = *(const float4*)(h + j);
        hreg[j] = q.x; hreg[j + 1] = q.y; hreg[j + 2] = q.z; hreg[j + 3] = q.w;
    }
    float mu = bm[0], dv = bd[0];
    #pragma unroll
    for (int j = 0; j < H_; ++j) {
        mu = __fmaf_rn(Wm[j], hreg[j], mu);
        dv = __fmaf_rn(Wd[j], hreg[j], dv);
    }
    r_out[n]  = y[n] - mu;
    dd_out[n] = log1pf(__expf(dv));   // softplus

    for (int k = 0; k < R_; ++k) {
        float acc = bv[k];
        #pragma unroll
        for (int j = 0; j < H_; ++j)
            acc = __fmaf_rn(Wv[k * H_ + j], hreg[j], acc);
        v_out[(size_t)n * R_ + k] = acc;
    }
}

__device__ __forceinline__ float block_reduce_sum256(float* red, int tid, float val)
{
    red[tid] = val;
    __syncthreads();
    for (int off = 128; off > 0; off >>= 1) {
        if (tid < off) red[tid] += red[tid + off];
        __syncthreads();
    }
    float r = red[0];
    __syncthreads();
    return r;
}

// ---------------------------------------------------------------------------
// Per-batch Woodbury: sigma = V V^T + D.
// quad  = r^T D^-1 r - u^T M^-1 u,  u = V^T D^-1 r,  M = I + V^T D^-1 V
// logdet= sum log d + logdet M  (32x32 Cholesky)
// ---------------------------------------------------------------------------
__global__ __launch_bounds__(256)
void woodbury_kernel(const float* __restrict__ v_in,
                     const float* __restrict__ dd_in,
                     const float* __restrict__ r_in,
                     float* __restrict__ batch_out)
{
    __shared__ float Vl[C_][R_ + 1];
    __shared__ float Vw[C_][R_ + 1];
    __shared__ float wi[C_];
    __shared__ float rl[C_];
    __shared__ float red[256];
    __shared__ float MA[R_][R_ + 1];
    __shared__ float uA[R_], yA[R_], wA[R_];

    const int tid = threadIdx.x;
    const int nb  = blockIdx.x * C_;

    for (int p = tid; p < C_ * R_; p += 256) {
        int cc = p >> 5, k = p & 31;
        Vl[cc][k] = v_in[(size_t)(nb + cc) * R_ + k];
    }
    float dval = dd_in[nb + tid];
    float winv = 1.0f / dval;
    float rv   = r_in[nb + tid];
    wi[tid] = winv;
    rl[tid] = rv;
    __syncthreads();

    for (int p = tid; p < C_ * R_; p += 256) {
        int cc = p >> 5, k = p & 31;
        Vw[cc][k] = Vl[cc][k] * wi[cc];
    }
    __syncthreads();

    float slogd = block_reduce_sum256(red, tid, __logf(dval));
    float rDr   = block_reduce_sum256(red, tid, rv * rv * winv);

    #pragma unroll
    for (int e = 0; e < 4; ++e) {
        int p = tid + e * 256;
        int i = p >> 5, j = p & 31;
        float acc = (i == j) ? 1.0f : 0.0f;
        for (int cc = 0; cc < C_; ++cc)
            acc = __fmaf_rn(Vw[cc][i], Vl[cc][j], acc);
        MA[i][j] = acc;
    }
    if (tid < R_) {
        float acc = 0.0f;
        for (int cc = 0; cc < C_; ++cc)
            acc = __fmaf_rn(Vw[cc][tid], rl[cc], acc);
        uA[tid] = acc;
    }
    __syncthreads();

    for (int k = 0; k < R_; ++k) {
        if (tid == 0) MA[k][k] = sqrtf(MA[k][k]);
        __syncthreads();
        if (tid > k && tid < R_) MA[tid][k] /= MA[k][k];
        __syncthreads();
        if (tid > k && tid < R_) {
            float ljk = MA[tid][k];
            for (int i2 = k + 1; i2 <= tid; ++i2)
                MA[tid][i2] -= ljk * MA[i2][k];
        }
        __syncthreads();
    }
    float ldm = block_reduce_sum256(red, tid,
                    (tid < R_) ? 2.0f * __logf(MA[tid][tid]) : 0.0f);

    if (tid == 0) {
        for (int k = 0; k < R_; ++k) {
            float sv = uA[k];
            for (int i2 = 0; i2 < k; ++i2) sv -= MA[k][i2] * yA[i2];
            yA[k] = sv / MA[k][k];
        }
        for (int k = R_ - 1; k >= 0; --k) {
            float sv = yA[k];
            for (int i2 = k + 1; i2 < R_; ++i2) sv -= MA[i2][k] * wA[i2];
            wA[k] = sv / MA[k][k];
        }
        float uw = 0.0f;
        for (int k = 0; k < R_; ++k) uw += wA[k] * uA[k];
        batch_out[blockIdx.x] = (rDr - uw) + slogd + ldm;
    }
}

__global__ void finalize_kernel(const float* __restrict__ bws, float* __restrict__ out)
{
    float v = bws[threadIdx.x];
    #pragma unroll
    for (int off = 32; off > 0; off >>= 1)
        v += __shfl_down(v, off, 64);
    if (threadIdx.x == 0) out[0] = v * (1.0f / 64.0f);
}

} // anonymous namespace

extern "C" void kernel_launch(void* const* d_in, const int* in_sizes, int n_in,
                              void* d_out, int out_size, void* d_ws, size_t ws_size,
                              hipStream_t stream)
{
    const float* x    = (const float*)d_in[0];
    const float* y    = (const float*)d_in[1];
    const float* Wih0 = (const float*)d_in[2];
    const float* Whh0 = (const float*)d_in[3];
    const float* bih0 = (const float*)d_in[4];
    const float* bhh0 = (const float*)d_in[5];
    const float* Wih1 = (const float*)d_in[6];
    const float* Whh1 = (const float*)d_in[7];
    const float* bih1 = (const float*)d_in[8];
    const float* bhh1 = (const float*)d_in[9];
    const float* Wm   = (const float*)d_in[10];
    const float* bm   = (const float*)d_in[11];
    const float* Wd   = (const float*)d_in[12];
    const float* bd   = (const float*)d_in[13];
    const float* Wv   = (const float*)d_in[14];
    const float* bv   = (const float*)d_in[15];

    char* ws = (char*)d_ws;
    float*    hT     = (float*)(ws + 0);                 // N*64 f32   (4 MB)
    float*    v_ws   = (float*)(ws + 4194304);           // N*32 f32   (2 MB)
    float*    dd_ws  = (float*)(ws + 6291456);           // N f32
    float*    r_ws   = (float*)(ws + 6356992);           // N f32
    float*    b_ws   = (float*)(ws + 6422528);           // B f32
    _Float16* packed = (_Float16*)(ws + 6423552);        // 4*18*512 fp16 (73728 B)

    pack_weights_kernel<<<72, 64, 0, stream>>>(Whh0, Wih1, Whh1, packed);
    gru_mfma_kernel<<<N_ / 16, 256, 0, stream>>>(
        x, packed, Wih0, bih0, bhh0, bih1, bhh1, hT);
    heads_kernel<<<N_ / 256, 256, 0, stream>>>(
        hT, y, Wm, bm, Wd, bd, Wv, bv, v_ws, dd_ws, r_ws);
    woodbury_kernel<<<B_, 256, 0, stream>>>(v_ws, dd_ws, r_ws, b_ws);
    finalize_kernel<<<1, 64, 0, stream>>>(b_ws, (float*)d_out);
}